// Round 6
// baseline (95.147 us; speedup 1.0000x reference)
//
#include <hip/hip_runtime.h>

// CenterLoss: loss = mean_b clip(||x_b - centers[labels[b]]||^2, 1e-12, 1e12)
//             + (C-1)*1e-12   (faithful replication of clipping the masked zeros)
//
// x: (8192,2048) f32   labels: (8192,) int   centers: (4096,2048) f32   out: scalar
//
// Single fused kernel (plus one 16 KB memset node):
//   phase 0: bucket samples by label (fixed-cap slots, 1 atomicAdd/sample)
//   grid barrier (device-scope fences + arrival counter; 512 blocks co-resident)
//   phase 2: one wave per 2 classes; center row held in 32 VGPRs, read ONCE
//            from memory per non-empty class (~21 MB instead of 64 MB gathered)
//   phase 3: exit ticket; last block reduces part[8192] -> scalar
//
// R1-R4 evidence: x (64 MB) + gathered centers (64 MB logical) saturate a
// shared ~6.9 TB/s fabric (L3 hits are not free). Deduping centers to ~21 MB
// unique is the only remaining traffic cut.

#define BATCH 8192
#define FEAT  2048
#define NCLS  4096
#define BLK   256
#define NBLK  512
#define CAP   16
#define WAVES_PER_BLK (BLK / 64)              // 4
#define NWAVE (NBLK * WAVES_PER_BLK)          // 2048
#define CLS_PER_WAVE (NCLS / NWAVE)           // 2

// d_ws int32 layout:
//   [0] barrier arrival counter     [1] exit ticket counter   [2..3] pad
//   [4 .. 4+NCLS)                   per-class count
//   [4+NCLS .. 4+NCLS+NCLS*CAP)     slots (sample indices)
//   then part[BATCH] floats (byte offset 278544, 16B-aligned)
#define OFF_CNT   4
#define OFF_SLOT  (OFF_CNT + NCLS)
#define OFF_PART  (OFF_SLOT + NCLS * CAP)
#define MEMSET_BYTES ((OFF_CNT + NCLS) * 4)   // counters + counts

__global__ void __launch_bounds__(BLK)
cl_all(const float* __restrict__ x,
       const int* __restrict__ labels,
       const float* __restrict__ centers,
       float* __restrict__ out,
       int* __restrict__ wsi) {
    const int tid  = threadIdx.x;
    const int bid  = blockIdx.x;
    const int wid  = tid >> 6;
    const int lane = tid & 63;

    int*   __restrict__ cnt   = wsi + OFF_CNT;
    int*   __restrict__ slots = wsi + OFF_SLOT;
    float* __restrict__ part  = (float*)(wsi + OFF_PART);

    __shared__ int   sticket;
    __shared__ float sred[WAVES_PER_BLK];

    // ---------------- phase 0: bucket by label ----------------
    const int gid = bid * BLK + tid;           // first 32 blocks do the work
    if (gid < BATCH) {
        const int l   = labels[gid];
        const int pos = atomicAdd(&cnt[l], 1);          // device-scope default
        if (pos < CAP) {
            slots[l * CAP + pos] = gid;
        } else {
            // overflow fallback (P ~ 1e-11/class at lambda=2): serial distance
            const float* xr = x + (size_t)gid * FEAT;
            const float* cr = centers + (size_t)l * FEAT;
            float acc = 0.0f;
            for (int j = 0; j < FEAT; ++j) {
                const float d = xr[j] - cr[j];
                acc += d * d;
            }
            part[gid] = fminf(fmaxf(acc, 1e-12f), 1e12f);
        }
    }

    // ---------------- grid barrier ----------------
    __syncthreads();
    if (tid == 0) {
        __builtin_amdgcn_fence(__ATOMIC_RELEASE, "agent");
        __hip_atomic_fetch_add(&wsi[0], 1, __ATOMIC_ACQ_REL, __HIP_MEMORY_SCOPE_AGENT);
        while (__hip_atomic_load(&wsi[0], __ATOMIC_ACQUIRE, __HIP_MEMORY_SCOPE_AGENT) < NBLK)
            __builtin_amdgcn_s_sleep(8);
    }
    __syncthreads();
    __builtin_amdgcn_fence(__ATOMIC_ACQUIRE, "agent");

    // ---------------- phase 2: per-class distances ----------------
    const int w = bid * WAVES_PER_BLK + wid;   // 0..2047
#pragma unroll
    for (int k = 0; k < CLS_PER_WAVE; ++k) {
        const int c  = w * CLS_PER_WAVE + k;
        const int n0 = cnt[c];
        if (n0 == 0) continue;
        const int n = n0 < CAP ? n0 : CAP;

        // center row -> registers (read once per non-empty class)
        const float4* __restrict__ cr =
            reinterpret_cast<const float4*>(centers + (size_t)c * FEAT);
        float4 cv[8];
#pragma unroll
        for (int j = 0; j < 8; ++j) cv[j] = cr[lane + j * 64];

        for (int i = 0; i < n; ++i) {
            const int b = slots[c * CAP + i];
            const float4* __restrict__ xr =
                reinterpret_cast<const float4*>(x + (size_t)b * FEAT);
            float4 xv[8];
#pragma unroll
            for (int j = 0; j < 8; ++j) xv[j] = xr[lane + j * 64];

            float a0 = 0.0f, a1 = 0.0f;
#pragma unroll
            for (int j = 0; j < 8; ++j) {
                const float d0 = xv[j].x - cv[j].x;
                const float d1 = xv[j].y - cv[j].y;
                const float d2 = xv[j].z - cv[j].z;
                const float d3 = xv[j].w - cv[j].w;
                a0 += d0 * d0 + d1 * d1;
                a1 += d2 * d2 + d3 * d3;
            }
            float acc = a0 + a1;
#pragma unroll
            for (int off = 32; off > 0; off >>= 1)
                acc += __shfl_down(acc, off, 64);
            if (lane == 0)
                part[b] = fminf(fmaxf(acc, 1e-12f), 1e12f);
        }
    }

    // ---------------- phase 3: last block reduces ----------------
    __syncthreads();
    if (tid == 0) {
        __builtin_amdgcn_fence(__ATOMIC_RELEASE, "agent");
        sticket = __hip_atomic_fetch_add(&wsi[1], 1, __ATOMIC_ACQ_REL,
                                         __HIP_MEMORY_SCOPE_AGENT);
    }
    __syncthreads();

    if (sticket == NBLK - 1) {
        __builtin_amdgcn_fence(__ATOMIC_ACQUIRE, "agent");
        const float4* __restrict__ pr = reinterpret_cast<const float4*>(part);
        float acc = 0.0f;
#pragma unroll
        for (int j = 0; j < BATCH / 4 / BLK; ++j) {      // 8 iterations
            const float4 v = pr[tid + j * BLK];
            acc += (v.x + v.y) + (v.z + v.w);
        }
#pragma unroll
        for (int off = 32; off > 0; off >>= 1)
            acc += __shfl_down(acc, off, 64);
        if (lane == 0) sred[wid] = acc;
        __syncthreads();
        if (tid == 0) {
            const float total = sred[0] + sred[1] + sred[2] + sred[3];
            // masked-zero entries: (BATCH*NCLS - BATCH) * 1e-12 / BATCH
            out[0] = total / (float)BATCH + (float)(NCLS - 1) * 1e-12f;
        }
    }
}

extern "C" void kernel_launch(void* const* d_in, const int* in_sizes, int n_in,
                              void* d_out, int out_size, void* d_ws, size_t ws_size,
                              hipStream_t stream) {
    const float* x       = (const float*)d_in[0];
    const int*   labels  = (const int*)d_in[1];
    const float* centers = (const float*)d_in[2];
    float* out = (float*)d_out;
    int*   wsi = (int*)d_ws;

    // zero barrier counters + per-class counts every call (graph-capturable)
    (void)hipMemsetAsync(d_ws, 0, MEMSET_BYTES, stream);
    cl_all<<<NBLK, BLK, 0, stream>>>(x, labels, centers, out, wsi);
}

// Round 7
// 80.691 us; speedup vs baseline: 1.1792x; 1.1792x over previous
//
#include <hip/hip_runtime.h>

// CenterLoss: loss = mean_b clip(||x_b - centers[labels[b]]||^2, 1e-12, 1e12)
//             + (C-1)*1e-12   (faithful replication of clipping the masked zeros)
//
// x: (8192,2048) f32   labels: (8192,) int   centers: (4096,2048) f32   out: scalar
//
// Kernel A: bucket samples by label (1 atomicAdd/sample, fixed-cap slots).
// Kernel B: ONE WAVE PER CLASS (4096 waves, 4/SIMD via __launch_bounds__(256,4));
//           center row pinned in 32 VGPRs (read once per class -> ~21 MB unique
//           instead of 64 MB gathered); samples pipelined 2-deep with named
//           register buffers (xa/xb). Finalize fused via exit ticket.
//
// R6 lessons fixed here: VGPR squeeze (48 -> cap 128), 2 waves/SIMD -> 4,
// class-pair stragglers -> one class/wave, grid barrier -> two kernels.

#define BATCH 8192
#define FEAT  2048
#define NCLS  4096
#define BLK   256
#define CAP   16
#define WAVES_PER_BLK (BLK / 64)              // 4
#define NBLK_B (NCLS / WAVES_PER_BLK)         // 1024 blocks for kernel B

// d_ws int32 layout:
//   [0] exit ticket counter   [1..3] pad
//   [4 .. 4+NCLS)                 per-class count
//   [4+NCLS .. 4+NCLS+NCLS*CAP)   slots (sample indices)
//   then part[BATCH] floats
#define OFF_CNT   4
#define OFF_SLOT  (OFF_CNT + NCLS)
#define OFF_PART  (OFF_SLOT + NCLS * CAP)
#define MEMSET_BYTES ((OFF_CNT + NCLS) * 4)   // ticket + counts

__global__ void __launch_bounds__(BLK)
cl_bucket(const float* __restrict__ x,
          const int* __restrict__ labels,
          const float* __restrict__ centers,
          int* __restrict__ wsi) {
    int*   __restrict__ cnt   = wsi + OFF_CNT;
    int*   __restrict__ slots = wsi + OFF_SLOT;
    float* __restrict__ part  = (float*)(wsi + OFF_PART);

    const int gid = blockIdx.x * BLK + threadIdx.x;      // 32 blocks cover BATCH
    const int l   = labels[gid];
    const int pos = atomicAdd(&cnt[l], 1);
    if (pos < CAP) {
        slots[l * CAP + pos] = gid;
    } else {
        // overflow fallback (P ~ 1e-9): serial per-thread distance
        const float* xr = x + (size_t)gid * FEAT;
        const float* cr = centers + (size_t)l * FEAT;
        float acc = 0.0f;
        for (int j = 0; j < FEAT; ++j) {
            const float d = xr[j] - cr[j];
            acc += d * d;
        }
        part[gid] = fminf(fmaxf(acc, 1e-12f), 1e12f);
    }
}

__global__ void __launch_bounds__(BLK, 4)     // cap 128 VGPR -> 4 waves/SIMD
cl_classes(const float* __restrict__ x,
           const int* __restrict__ labels,
           const float* __restrict__ centers,
           float* __restrict__ out,
           int* __restrict__ wsi) {
    const int tid  = threadIdx.x;
    const int bid  = blockIdx.x;
    const int wid  = tid >> 6;
    const int lane = tid & 63;

    int*   __restrict__ cnt   = wsi + OFF_CNT;
    int*   __restrict__ slots = wsi + OFF_SLOT;
    float* __restrict__ part  = (float*)(wsi + OFF_PART);

    __shared__ int   sticket;
    __shared__ float sred[WAVES_PER_BLK];

    const int c    = bid * WAVES_PER_BLK + wid;          // class for this wave
    const int n0   = cnt[c];
    const int base = c * CAP;

    if (n0 > 0) {
        const int n = n0 < CAP ? n0 : CAP;

        // center row -> 32 VGPRs, read once per class
        const float4* __restrict__ cr =
            reinterpret_cast<const float4*>(centers + (size_t)c * FEAT);
        float4 cv[8];
#pragma unroll
        for (int j = 0; j < 8; ++j) cv[j] = cr[lane + j * 64];

        float4 xa[8], xb[8];

#define ISSUE(BUF, B)                                                          \
        {                                                                      \
            const float4* __restrict__ xr =                                    \
                reinterpret_cast<const float4*>(x + (size_t)(B) * FEAT);       \
            _Pragma("unroll")                                                  \
            for (int j = 0; j < 8; ++j) BUF[j] = xr[lane + j * 64];            \
        }

#define COMPUTE(BUF, B)                                                        \
        {                                                                      \
            float a0 = 0.0f, a1 = 0.0f;                                        \
            _Pragma("unroll")                                                  \
            for (int j = 0; j < 8; ++j) {                                      \
                const float d0 = BUF[j].x - cv[j].x;                           \
                const float d1 = BUF[j].y - cv[j].y;                           \
                const float d2 = BUF[j].z - cv[j].z;                           \
                const float d3 = BUF[j].w - cv[j].w;                           \
                a0 += d0 * d0 + d1 * d1;                                       \
                a1 += d2 * d2 + d3 * d3;                                       \
            }                                                                  \
            float acc = a0 + a1;                                               \
            _Pragma("unroll")                                                  \
            for (int off = 32; off > 0; off >>= 1)                             \
                acc += __shfl_down(acc, off, 64);                              \
            if (lane == 0)                                                     \
                part[B] = fminf(fmaxf(acc, 1e-12f), 1e12f);                    \
        }

        // 2-deep software pipeline over this class's samples
        int i  = 0;
        int bA = slots[base + 0];
        ISSUE(xa, bA);
        while (true) {
            int bB = 0;
            const bool haveB = (i + 1 < n);
            if (haveB) { bB = slots[base + i + 1]; ISSUE(xb, bB); }
            COMPUTE(xa, bA);
            if (!haveB) break;
            ++i;
            const bool haveA = (i + 1 < n);
            if (haveA) { bA = slots[base + i + 1]; ISSUE(xa, bA); }
            COMPUTE(xb, bB);
            if (!haveA) break;
            ++i;
        }
#undef ISSUE
#undef COMPUTE
    }

    // ---------------- exit-ticket finalize ----------------
    __syncthreads();
    if (tid == 0) {
        __builtin_amdgcn_fence(__ATOMIC_RELEASE, "agent");
        sticket = __hip_atomic_fetch_add(&wsi[0], 1, __ATOMIC_ACQ_REL,
                                         __HIP_MEMORY_SCOPE_AGENT);
    }
    __syncthreads();

    if (sticket == NBLK_B - 1) {
        __builtin_amdgcn_fence(__ATOMIC_ACQUIRE, "agent");
        const float4* __restrict__ pr = reinterpret_cast<const float4*>(part);
        float acc = 0.0f;
#pragma unroll
        for (int j = 0; j < BATCH / 4 / BLK; ++j) {      // 8 iterations
            const float4 v = pr[tid + j * BLK];
            acc += (v.x + v.y) + (v.z + v.w);
        }
#pragma unroll
        for (int off = 32; off > 0; off >>= 1)
            acc += __shfl_down(acc, off, 64);
        if (lane == 0) sred[wid] = acc;
        __syncthreads();
        if (tid == 0) {
            const float total = sred[0] + sred[1] + sred[2] + sred[3];
            // masked-zero entries: (BATCH*NCLS - BATCH) * 1e-12 / BATCH
            out[0] = total / (float)BATCH + (float)(NCLS - 1) * 1e-12f;
        }
    }
}

extern "C" void kernel_launch(void* const* d_in, const int* in_sizes, int n_in,
                              void* d_out, int out_size, void* d_ws, size_t ws_size,
                              hipStream_t stream) {
    const float* x       = (const float*)d_in[0];
    const int*   labels  = (const int*)d_in[1];
    const float* centers = (const float*)d_in[2];
    float* out = (float*)d_out;
    int*   wsi = (int*)d_ws;

    (void)hipMemsetAsync(d_ws, 0, MEMSET_BYTES, stream);
    cl_bucket<<<BATCH / BLK, BLK, 0, stream>>>(x, labels, centers, wsi);
    cl_classes<<<NBLK_B, BLK, 0, stream>>>(x, labels, centers, out, wsi);
}